// Round 2
// baseline (527.630 us; speedup 1.0000x reference)
//
#include <hip/hip_runtime.h>

typedef __attribute__((ext_vector_type(8))) short bf16x8;
typedef __attribute__((ext_vector_type(4))) float f32x4;

#define MFMA(a, b, c) __builtin_amdgcn_mfma_f32_16x16x32_bf16((a), (b), (c), 0, 0, 0)

__device__ __forceinline__ short f2bf(float f) {
    union { float f; unsigned u; } v; v.f = f;
    unsigned r = v.u + 0x7fffu + ((v.u >> 16) & 1u);   // RNE
    return (short)(r >> 16);
}
__device__ __forceinline__ float bf2f(short h) {
    union { unsigned u; float f; } v;
    v.u = ((unsigned)(unsigned short)h) << 16;
    return v.f;
}
__device__ __forceinline__ void wsplit(float w, short& hi, short& lo) {
    hi = f2bf(w);
    lo = f2bf(w - bf2f(hi));
}
__device__ __forceinline__ float tanh_fast(float x) {
    // tanh(x) = 1 - 2/(e^{2x}+1); exp2-based, saturates correctly at +/-inf
    float z = __builtin_amdgcn_exp2f(x * 2.8853900817779268f); // 2*log2(e)
    return 1.0f - 2.0f * __builtin_amdgcn_rcpf(z + 1.0f);
}

// B fragment pair: Bhi[k slot i] = bf16(W[j][m]), Blo = bf16 residual, m = kbase+i.
// (computing h @ W^T:  B[k][j] = W[j*50+k], zero-padded)
__device__ __forceinline__ void makeB2(const float* __restrict__ W, int j, int kbase,
                                       bf16x8& Bhi, bf16x8& Blo) {
#pragma unroll
    for (int i = 0; i < 8; ++i) {
        int m = kbase + i;
        short h = 0, l = 0;
        if (j < 50 && m < 50) wsplit(W[j * 50 + m], h, l);
        Bhi[i] = h; Blo[i] = l;
    }
}

// --- LDS tile: [16 rows][128 cols] bf16 (256B rows). cols 0-63 = hi, 64-127 = lo.
// XOR-swizzle byte bits 4-7 with row (bijective within the 256B row) -> <=2-way banks.
__device__ __forceinline__ int swz(int row, int byteInRow) {
    return (row << 8) + (byteInRow ^ ((row & 15) << 4));
}
__device__ __forceinline__ bf16x8 ldsA(const short* buf, int row, int kblk, int g) {
    return *(const bf16x8*)((const char*)buf + swz(row, (kblk << 6) + (g << 4)));
}
__device__ __forceinline__ void ldsW(short* buf, int row, int col, short v) {
    *(short*)((char*)buf + swz(row, col << 1)) = v;
}
__device__ __forceinline__ float ldsR(const short* buf, int row, int col) {
    return bf2f(*(const short*)((const char*)buf + swz(row, col << 1)));
}

__global__ __launch_bounds__(256, 1)
void rnn3_kernel(const float* __restrict__ x,
                 const float* __restrict__ Wih1, const float* __restrict__ Whh1,
                 const float* __restrict__ bih1, const float* __restrict__ bhh1,
                 const float* __restrict__ Wih2, const float* __restrict__ Whh2,
                 const float* __restrict__ bih2, const float* __restrict__ bhh2,
                 const float* __restrict__ Wih3, const float* __restrict__ Whh3,
                 const float* __restrict__ bih3, const float* __restrict__ bhh3,
                 const float* __restrict__ Wfc,  const float* __restrict__ bfc,
                 float* __restrict__ out)
{
    // h state: bf16 hi|lo [16][128], double buffered
    __shared__ __align__(16) short h1b[2][2048];
    __shared__ __align__(16) short h2b[2][2048];
    __shared__ __align__(16) short h3b[2][2048];
    __shared__ float x_lds[512 * 16];   // [t][b]

    const int tid  = threadIdx.x;
    const int lane = tid & 63;
    const int w    = tid >> 6;        // wave id 0..3 -> 16-col N-stripe
    const int g    = lane >> 4;       // k-group
    const int rowA = lane & 15;       // A-frag row = batch row (0..15, all real)
    const int jcol = (w << 4) | rowA; // hidden col 0..63 (valid < 50)
    const int rowC0 = g << 2;         // C-frag base row
    const int b0   = blockIdx.x * 16; // batch chunk

    // ---- zero-init h state (h0 = 0) ----
    { int* z = (int*)h1b; for (int i = tid; i < 2048; i += 256) z[i] = 0; }
    { int* z = (int*)h2b; for (int i = tid; i < 2048; i += 256) z[i] = 0; }
    { int* z = (int*)h3b; for (int i = tid; i < 2048; i += 256) z[i] = 0; }

    // ---- stage x[b0..b0+15][0..511] -> x_lds[t*16+b] ----
    {
        const float4* xg = (const float4*)(x + (size_t)b0 * 512);
        for (int i = tid; i < 2048; i += 256) {   // 16 rows * 128 float4
            float4 v = xg[i];
            int b = i >> 7, t0 = (i & 127) << 2;
            x_lds[(t0 + 0) * 16 + b] = v.x;
            x_lds[(t0 + 1) * 16 + b] = v.y;
            x_lds[(t0 + 2) * 16 + b] = v.z;
            x_lds[(t0 + 3) * 16 + b] = v.w;
        }
    }

    // ---- persistent per-wave B fragments (hi + lo residual) ----
    const int k8 = g << 3;
    bf16x8 Bhh1_h0, Bhh1_l0, Bhh1_h1, Bhh1_l1;
    makeB2(Whh1, jcol, k8,      Bhh1_h0, Bhh1_l0);
    makeB2(Whh1, jcol, 32 + k8, Bhh1_h1, Bhh1_l1);
    bf16x8 Bih2_h0, Bih2_l0, Bih2_h1, Bih2_l1;
    makeB2(Wih2, jcol, k8,      Bih2_h0, Bih2_l0);
    makeB2(Wih2, jcol, 32 + k8, Bih2_h1, Bih2_l1);
    bf16x8 Bhh2_h0, Bhh2_l0, Bhh2_h1, Bhh2_l1;
    makeB2(Whh2, jcol, k8,      Bhh2_h0, Bhh2_l0);
    makeB2(Whh2, jcol, 32 + k8, Bhh2_h1, Bhh2_l1);
    bf16x8 Bih3_h0, Bih3_l0, Bih3_h1, Bih3_l1;
    makeB2(Wih3, jcol, k8,      Bih3_h0, Bih3_l0);
    makeB2(Wih3, jcol, 32 + k8, Bih3_h1, Bih3_l1);
    bf16x8 Bhh3_h0, Bhh3_l0, Bhh3_h1, Bhh3_l1;
    makeB2(Whh3, jcol, k8,      Bhh3_h0, Bhh3_l0);
    makeB2(Whh3, jcol, 32 + k8, Bhh3_h1, Bhh3_l1);

    // x-extension fragment: slots [Whi, Whi, Wlo] pair with xa = [x_hi, x_lo, x_hi]
    bf16x8 B1x;
#pragma unroll
    for (int i = 0; i < 8; ++i) B1x[i] = 0;
    if (g == 0 && jcol < 50) {
        short h, l; wsplit(Wih1[jcol], h, l);
        B1x[0] = h; B1x[1] = h; B1x[2] = l;
    }

    const float bias1 = (jcol < 50) ? (bih1[jcol] + bhh1[jcol]) : 0.0f;
    const float bias2 = (jcol < 50) ? (bih2[jcol] + bhh2[jcol]) : 0.0f;
    const float bias3 = (jcol < 50) ? (bih3[jcol] + bhh3[jcol]) : 0.0f;

    __syncthreads();

    // ---- time loop: 2 barriers per step (ping-pong) ----
#pragma unroll 2
    for (int t = 0; t < 512; ++t) {
        const int p = t & 1, q = p ^ 1;

        // ----- Layer 1: h1' = tanh(bias1 + h1@Whh1^T + x*Wih1^T) -----
        float xv = x_lds[t * 16 + rowA];
        short xh = f2bf(xv);
        short xl = f2bf(xv - bf2f(xh));
        bf16x8 xa;
#pragma unroll
        for (int i = 0; i < 8; ++i) xa[i] = 0;
        if (g == 0) { xa[0] = xh; xa[1] = xl; xa[2] = xh; }

        bf16x8 a0 = ldsA(h1b[p], rowA, 0, g);   // hi
        bf16x8 a1 = ldsA(h1b[p], rowA, 1, g);
        bf16x8 a2 = ldsA(h1b[p], rowA, 2, g);   // lo
        bf16x8 a3 = ldsA(h1b[p], rowA, 3, g);
        f32x4 c0; c0[0] = bias1; c0[1] = bias1; c0[2] = bias1; c0[3] = bias1;
        f32x4 c1; c1[0] = 0.f; c1[1] = 0.f; c1[2] = 0.f; c1[3] = 0.f;
        c0 = MFMA(a0, Bhh1_h0, c0);  c0 = MFMA(a1, Bhh1_h1, c0);   // hi*Whi
        c1 = MFMA(a0, Bhh1_l0, c1);  c1 = MFMA(a1, Bhh1_l1, c1);   // hi*Wlo
        c0 = MFMA(a2, Bhh1_h0, c0);  c0 = MFMA(a3, Bhh1_h1, c0);   // lo*Whi
        c1 = MFMA(xa, B1x, c1);                                    // x-term
#pragma unroll
        for (int r = 0; r < 4; ++r) {
            float tv = tanh_fast(c0[r] + c1[r]);
            short hh = f2bf(tv);
            short hl = f2bf(tv - bf2f(hh));
            ldsW(h1b[q], rowC0 + r, jcol, hh);
            ldsW(h1b[q], rowC0 + r, 64 + jcol, hl);
        }
        __syncthreads();   // h1' visible

        // ----- Layer 2: h2' = tanh(bias2 + h1'@Wih2^T + h2@Whh2^T) -----
        a0 = ldsA(h1b[q], rowA, 0, g);  a1 = ldsA(h1b[q], rowA, 1, g);
        a2 = ldsA(h1b[q], rowA, 2, g);  a3 = ldsA(h1b[q], rowA, 3, g);
        bf16x8 a4 = ldsA(h2b[p], rowA, 0, g), a5 = ldsA(h2b[p], rowA, 1, g);
        bf16x8 a6 = ldsA(h2b[p], rowA, 2, g), a7 = ldsA(h2b[p], rowA, 3, g);
        c0[0] = bias2; c0[1] = bias2; c0[2] = bias2; c0[3] = bias2;
        c1[0] = 0.f; c1[1] = 0.f; c1[2] = 0.f; c1[3] = 0.f;
        c0 = MFMA(a0, Bih2_h0, c0);  c0 = MFMA(a1, Bih2_h1, c0);
        c1 = MFMA(a0, Bih2_l0, c1);  c1 = MFMA(a1, Bih2_l1, c1);
        c0 = MFMA(a2, Bih2_h0, c0);  c0 = MFMA(a3, Bih2_h1, c0);
        c1 = MFMA(a4, Bhh2_h0, c1);  c1 = MFMA(a5, Bhh2_h1, c1);
        c0 = MFMA(a4, Bhh2_l0, c0);  c0 = MFMA(a5, Bhh2_l1, c0);
        c1 = MFMA(a6, Bhh2_h0, c1);  c1 = MFMA(a7, Bhh2_h1, c1);
#pragma unroll
        for (int r = 0; r < 4; ++r) {
            float tv = tanh_fast(c0[r] + c1[r]);
            short hh = f2bf(tv);
            short hl = f2bf(tv - bf2f(hh));
            ldsW(h2b[q], rowC0 + r, jcol, hh);
            ldsW(h2b[q], rowC0 + r, 64 + jcol, hl);
        }
        __syncthreads();   // h2' visible

        // ----- Layer 3: h3' = tanh(bias3 + h2'@Wih3^T + h3@Whh3^T) -----
        a0 = ldsA(h2b[q], rowA, 0, g);  a1 = ldsA(h2b[q], rowA, 1, g);
        a2 = ldsA(h2b[q], rowA, 2, g);  a3 = ldsA(h2b[q], rowA, 3, g);
        a4 = ldsA(h3b[p], rowA, 0, g);  a5 = ldsA(h3b[p], rowA, 1, g);
        a6 = ldsA(h3b[p], rowA, 2, g);  a7 = ldsA(h3b[p], rowA, 3, g);
        c0[0] = bias3; c0[1] = bias3; c0[2] = bias3; c0[3] = bias3;
        c1[0] = 0.f; c1[1] = 0.f; c1[2] = 0.f; c1[3] = 0.f;
        c0 = MFMA(a0, Bih3_h0, c0);  c0 = MFMA(a1, Bih3_h1, c0);
        c1 = MFMA(a0, Bih3_l0, c1);  c1 = MFMA(a1, Bih3_l1, c1);
        c0 = MFMA(a2, Bih3_h0, c0);  c0 = MFMA(a3, Bih3_h1, c0);
        c1 = MFMA(a4, Bhh3_h0, c1);  c1 = MFMA(a5, Bhh3_h1, c1);
        c0 = MFMA(a4, Bhh3_l0, c0);  c0 = MFMA(a5, Bhh3_l1, c0);
        c1 = MFMA(a6, Bhh3_h0, c1);  c1 = MFMA(a7, Bhh3_h1, c1);
#pragma unroll
        for (int r = 0; r < 4; ++r) {
            float tv = tanh_fast(c0[r] + c1[r]);
            short hh = f2bf(tv);
            short hl = f2bf(tv - bf2f(hh));
            ldsW(h3b[q], rowC0 + r, jcol, hh);
            ldsW(h3b[q], rowC0 + r, 64 + jcol, hl);
        }
        // no barrier: next step's hazards covered by its own two barriers
    }
    __syncthreads();

    // ---- FC epilogue: out[b][o] = (h3_hi + h3_lo) @ Wfc^T + bfc ----
    // final h3 buffer: t=511 -> q = 0
    if (w == 0) {
        const short* h3f = h3b[0];
        int b = lane & 15, og = lane >> 4;          // 16 batch x 4 output groups
        for (int o = og; o < 10; o += 4) {
            float acc = bfc[o];
            for (int k = 0; k < 50; ++k)
                acc += (ldsR(h3f, b, k) + ldsR(h3f, b, 64 + k)) * Wfc[o * 50 + k];
            out[(size_t)(b0 + b) * 10 + o] = acc;
        }
    }
}

extern "C" void kernel_launch(void* const* d_in, const int* in_sizes, int n_in,
                              void* d_out, int out_size, void* d_ws, size_t ws_size,
                              hipStream_t stream) {
    const float* x    = (const float*)d_in[0];
    const float* Wih1 = (const float*)d_in[1];
    const float* Whh1 = (const float*)d_in[2];
    const float* bih1 = (const float*)d_in[3];
    const float* bhh1 = (const float*)d_in[4];
    const float* Wih2 = (const float*)d_in[5];
    const float* Whh2 = (const float*)d_in[6];
    const float* bih2 = (const float*)d_in[7];
    const float* bhh2 = (const float*)d_in[8];
    const float* Wih3 = (const float*)d_in[9];
    const float* Whh3 = (const float*)d_in[10];
    const float* bih3 = (const float*)d_in[11];
    const float* bhh3 = (const float*)d_in[12];
    const float* Wfc  = (const float*)d_in[13];
    const float* bfc  = (const float*)d_in[14];
    float* out = (float*)d_out;

    dim3 grid(256), block(256);   // 16 batch rows per block, 4 waves (N-stripes)
    hipLaunchKernelGGL(rnn3_kernel, grid, block, 0, stream,
                       x, Wih1, Whh1, bih1, bhh1,
                       Wih2, Whh2, bih2, bhh2,
                       Wih3, Whh3, bih3, bhh3,
                       Wfc, bfc, out);
}

// Round 3
// 463.951 us; speedup vs baseline: 1.1373x; 1.1373x over previous
//
#include <hip/hip_runtime.h>

typedef __attribute__((ext_vector_type(8))) short bf16x8;
typedef __attribute__((ext_vector_type(4))) float f32x4;

#define MFMA(a, b, c) __builtin_amdgcn_mfma_f32_16x16x32_bf16((a), (b), (c), 0, 0, 0)

__device__ __forceinline__ short f2bf(float f) {
    union { float f; unsigned u; } v; v.f = f;
    unsigned r = v.u + 0x7fffu + ((v.u >> 16) & 1u);   // RNE
    return (short)(r >> 16);
}
__device__ __forceinline__ float bf2f(short h) {
    union { unsigned u; float f; } v;
    v.u = ((unsigned)(unsigned short)h) << 16;
    return v.f;
}
__device__ __forceinline__ void wsplit(float w, short& hi, short& lo) {
    hi = f2bf(w);
    lo = f2bf(w - bf2f(hi));
}
__device__ __forceinline__ float tanh_fast(float x) {
    float z = __builtin_amdgcn_exp2f(x * 2.8853900817779268f); // 2*log2(e)
    return 1.0f - 2.0f * __builtin_amdgcn_rcpf(z + 1.0f);
}
// packed bf16 convert: [15:0]=bf16(a), [31:16]=bf16(b). Pure VALU asm (safe to reorder).
__device__ __forceinline__ unsigned cvt_pk_bf16(float a, float b) {
    unsigned r;
    asm("v_cvt_pk_bf16_f32 %0, %1, %2" : "=v"(r) : "v"(a), "v"(b));
    return r;
}

// B fragment pair: hi + bf16 residual, B[k][j] = W[j*50+k] (h @ W^T), zero-padded.
__device__ __forceinline__ void makeB2(const float* __restrict__ W, int j, int kbase,
                                       bf16x8& Bhi, bf16x8& Blo) {
#pragma unroll
    for (int i = 0; i < 8; ++i) {
        int m = kbase + i;
        short h = 0, l = 0;
        if (j < 50 && m < 50) wsplit(W[j * 50 + m], h, l);
        Bhi[i] = h; Blo[i] = l;
    }
}

// --- LDS tile: [16 rows][128 cols] bf16 (256B rows). cols 0-63 = hi, 64-127 = lo.
__device__ __forceinline__ int swz(int row, int byteInRow) {
    return (row << 8) + (byteInRow ^ ((row & 15) << 4));
}
__device__ __forceinline__ bf16x8 ldsA(const short* buf, int row, int kblk, int g) {
    return *(const bf16x8*)((const char*)buf + swz(row, (kblk << 6) + (g << 4)));
}
__device__ __forceinline__ float ldsR(const short* buf, int row, int col) {
    return bf2f(*(const short*)((const char*)buf + swz(row, col << 1)));
}
// store two consecutive C rows (hi+lo split) via packed converts
__device__ __forceinline__ void store_pair(short* wbuf, int row0, int jcol, float v0, float v1) {
    unsigned hp = cvt_pk_bf16(v0, v1);
    float h0 = bf2f((short)hp), h1 = bf2f((short)(hp >> 16));
    unsigned lp = cvt_pk_bf16(v0 - h0, v1 - h1);
    *(short*)((char*)wbuf + swz(row0,     jcol << 1))        = (short)hp;
    *(short*)((char*)wbuf + swz(row0 + 1, jcol << 1))        = (short)(hp >> 16);
    *(short*)((char*)wbuf + swz(row0,     (64 + jcol) << 1)) = (short)lp;
    *(short*)((char*)wbuf + swz(row0 + 1, (64 + jcol) << 1)) = (short)(lp >> 16);
}

// full layer (ih on forward input i*, hh on state s*): 12 MFMAs, 4 accum chains of 3
__device__ __forceinline__ void layer_full(
    const bf16x8& i0, const bf16x8& i1, const bf16x8& i2, const bf16x8& i3,
    const bf16x8& s0, const bf16x8& s1, const bf16x8& s2, const bf16x8& s3,
    const bf16x8& Bih_h0, const bf16x8& Bih_h1, const bf16x8& Bih_l0, const bf16x8& Bih_l1,
    const bf16x8& Bhh_h0, const bf16x8& Bhh_h1, const bf16x8& Bhh_l0, const bf16x8& Bhh_l1,
    float bias, short* wbuf, int rowC0, int jcol)
{
    f32x4 a0 = {bias, bias, bias, bias};
    f32x4 a1 = {0.f, 0.f, 0.f, 0.f}, a2 = {0.f, 0.f, 0.f, 0.f}, a3 = {0.f, 0.f, 0.f, 0.f};
    a0 = MFMA(i0, Bih_h0, a0);  a1 = MFMA(i1, Bih_h1, a1);
    a2 = MFMA(s0, Bhh_h0, a2);  a3 = MFMA(s1, Bhh_h1, a3);
    a0 = MFMA(i2, Bih_h0, a0);  a1 = MFMA(i3, Bih_h1, a1);
    a2 = MFMA(s2, Bhh_h0, a2);  a3 = MFMA(s3, Bhh_h1, a3);
    a0 = MFMA(s0, Bhh_l0, a0);  a1 = MFMA(s1, Bhh_l1, a1);
    a2 = MFMA(i0, Bih_l0, a2);  a3 = MFMA(i1, Bih_l1, a3);
    float t0 = tanh_fast(a0[0] + a1[0] + a2[0] + a3[0]);
    float t1 = tanh_fast(a0[1] + a1[1] + a2[1] + a3[1]);
    float t2 = tanh_fast(a0[2] + a1[2] + a2[2] + a3[2]);
    float t3 = tanh_fast(a0[3] + a1[3] + a2[3] + a3[3]);
    store_pair(wbuf, rowC0,     jcol, t0, t1);
    store_pair(wbuf, rowC0 + 2, jcol, t2, t3);
}

// layer 1 (hh on state + rank-1 x term): 7 MFMAs, 3 accum chains
__device__ __forceinline__ void layer1(
    const bf16x8& s0, const bf16x8& s1, const bf16x8& s2, const bf16x8& s3,
    const bf16x8& xa,
    const bf16x8& Bh0, const bf16x8& Bh1, const bf16x8& Bl0, const bf16x8& Bl1,
    const bf16x8& Bx,
    float bias, short* wbuf, int rowC0, int jcol)
{
    f32x4 a0 = {bias, bias, bias, bias};
    f32x4 a1 = {0.f, 0.f, 0.f, 0.f}, a2 = {0.f, 0.f, 0.f, 0.f};
    a0 = MFMA(s0, Bh0, a0);  a1 = MFMA(s1, Bh1, a1);  a2 = MFMA(s0, Bl0, a2);
    a0 = MFMA(s2, Bh0, a0);  a1 = MFMA(s3, Bh1, a1);  a2 = MFMA(s1, Bl1, a2);
    a2 = MFMA(xa, Bx, a2);
    float t0 = tanh_fast(a0[0] + a1[0] + a2[0]);
    float t1 = tanh_fast(a0[1] + a1[1] + a2[1]);
    float t2 = tanh_fast(a0[2] + a1[2] + a2[2]);
    float t3 = tanh_fast(a0[3] + a1[3] + a2[3]);
    store_pair(wbuf, rowC0,     jcol, t0, t1);
    store_pair(wbuf, rowC0 + 2, jcol, t2, t3);
}

__global__ __launch_bounds__(256, 1)
void rnn3_kernel(const float* __restrict__ x,
                 const float* __restrict__ Wih1, const float* __restrict__ Whh1,
                 const float* __restrict__ bih1, const float* __restrict__ bhh1,
                 const float* __restrict__ Wih2, const float* __restrict__ Whh2,
                 const float* __restrict__ bih2, const float* __restrict__ bhh2,
                 const float* __restrict__ Wih3, const float* __restrict__ Whh3,
                 const float* __restrict__ bih3, const float* __restrict__ bhh3,
                 const float* __restrict__ Wfc,  const float* __restrict__ bfc,
                 float* __restrict__ out)
{
    __shared__ __align__(16) short h1b[2][2048];
    __shared__ __align__(16) short h2b[2][2048];
    __shared__ __align__(16) short h3b[2][2048];
    __shared__ unsigned xp[512 * 16];   // x pre-split: lo16=x_hi(bf16), hi16=x_lo(bf16)

    const int tid  = threadIdx.x;
    const int lane = tid & 63;
    const int w    = tid >> 6;
    const int g    = lane >> 4;
    const int rowA = lane & 15;
    const int jcol = (w << 4) | rowA;
    const int rowC0 = g << 2;
    const int b0   = blockIdx.x * 16;

    // ---- stage x, pre-split into bf16 hi/lo ----
    {
        const float4* xg = (const float4*)(x + (size_t)b0 * 512);
        for (int idx = tid; idx < 2048; idx += 256) {
            float4 v = xg[idx];
            int b = idx >> 7, t0 = (idx & 127) << 2;
            float vv[4] = {v.x, v.y, v.z, v.w};
#pragma unroll
            for (int j = 0; j < 4; ++j) {
                short h, l; wsplit(vv[j], h, l);
                xp[(t0 + j) * 16 + b] = (unsigned)(unsigned short)h
                                      | ((unsigned)(unsigned short)l << 16);
            }
        }
    }

    // ---- persistent B fragments ----
    const int k8 = g << 3;
    bf16x8 Bhh1_h0, Bhh1_l0, Bhh1_h1, Bhh1_l1;
    makeB2(Whh1, jcol, k8,      Bhh1_h0, Bhh1_l0);
    makeB2(Whh1, jcol, 32 + k8, Bhh1_h1, Bhh1_l1);
    bf16x8 Bih2_h0, Bih2_l0, Bih2_h1, Bih2_l1;
    makeB2(Wih2, jcol, k8,      Bih2_h0, Bih2_l0);
    makeB2(Wih2, jcol, 32 + k8, Bih2_h1, Bih2_l1);
    bf16x8 Bhh2_h0, Bhh2_l0, Bhh2_h1, Bhh2_l1;
    makeB2(Whh2, jcol, k8,      Bhh2_h0, Bhh2_l0);
    makeB2(Whh2, jcol, 32 + k8, Bhh2_h1, Bhh2_l1);
    bf16x8 Bih3_h0, Bih3_l0, Bih3_h1, Bih3_l1;
    makeB2(Wih3, jcol, k8,      Bih3_h0, Bih3_l0);
    makeB2(Wih3, jcol, 32 + k8, Bih3_h1, Bih3_l1);
    bf16x8 Bhh3_h0, Bhh3_l0, Bhh3_h1, Bhh3_l1;
    makeB2(Whh3, jcol, k8,      Bhh3_h0, Bhh3_l0);
    makeB2(Whh3, jcol, 32 + k8, Bhh3_h1, Bhh3_l1);

    bf16x8 B1x = {0,0,0,0,0,0,0,0};
    if (g == 0 && jcol < 50) {
        short h, l; wsplit(Wih1[jcol], h, l);
        B1x[0] = h; B1x[1] = h; B1x[2] = l;   // pairs with xa = [x_hi, x_lo, x_hi]
    }
    const float bias1 = (jcol < 50) ? (bih1[jcol] + bhh1[jcol]) : 0.0f;
    const float bias2 = (jcol < 50) ? (bih2[jcol] + bhh2[jcol]) : 0.0f;
    const float bias3 = (jcol < 50) ? (bih3[jcol] + bhh3[jcol]) : 0.0f;

    __syncthreads();   // x staged (no LDS zero-init needed: all h reads pre-first-write are via zero regs)

    // register-held states (all zero = h(-1))
    bf16x8 s1_0 = {0,0,0,0,0,0,0,0}, s1_1 = s1_0, s1_2 = s1_0, s1_3 = s1_0; // h1 state
    bf16x8 f2_0 = s1_0, f2_1 = s1_0, f2_2 = s1_0, f2_3 = s1_0;              // h2 state / fwd
    bf16x8 s3_0 = s1_0, s3_1 = s1_0, s3_2 = s1_0, s3_3 = s1_0;              // h3 state

    // ---- peel i=0:  A: L1(0)   B: L2(0) ----
    {
        bf16x8 xa = {0,0,0,0,0,0,0,0};
        if (g == 0) {
            unsigned xw = xp[rowA];
            xa[0] = (short)xw; xa[1] = (short)(xw >> 16); xa[2] = (short)xw;
        }
        layer1(s1_0, s1_1, s1_2, s1_3, xa, Bhh1_h0, Bhh1_h1, Bhh1_l0, Bhh1_l1, B1x,
               bias1, h1b[0], rowC0, jcol);
        __syncthreads();
        s1_0 = ldsA(h1b[0], rowA, 0, g);  s1_1 = ldsA(h1b[0], rowA, 1, g);
        s1_2 = ldsA(h1b[0], rowA, 2, g);  s1_3 = ldsA(h1b[0], rowA, 3, g);
        layer_full(s1_0, s1_1, s1_2, s1_3, f2_0, f2_1, f2_2, f2_3,
                   Bih2_h0, Bih2_h1, Bih2_l0, Bih2_l1,
                   Bhh2_h0, Bhh2_h1, Bhh2_l0, Bhh2_l1,
                   bias2, h2b[0], rowC0, jcol);
        __syncthreads();
    }

    // ---- main loop: A = {L3(i-1), L1(i)}, B = {L2(i)} ----
#pragma unroll 2
    for (int i = 1; i < 512; ++i) {
        const int pe = i & 1, po = pe ^ 1;

        // Region A: fresh h2'(i-1); L1(i) on reg state; L3(i-1) on fresh + reg state
        f2_0 = ldsA(h2b[po], rowA, 0, g);  f2_1 = ldsA(h2b[po], rowA, 1, g);
        f2_2 = ldsA(h2b[po], rowA, 2, g);  f2_3 = ldsA(h2b[po], rowA, 3, g);
        bf16x8 xa = {0,0,0,0,0,0,0,0};
        if (g == 0) {
            unsigned xw = xp[i * 16 + rowA];
            xa[0] = (short)xw; xa[1] = (short)(xw >> 16); xa[2] = (short)xw;
        }
        layer1(s1_0, s1_1, s1_2, s1_3, xa, Bhh1_h0, Bhh1_h1, Bhh1_l0, Bhh1_l1, B1x,
               bias1, h1b[pe], rowC0, jcol);
        layer_full(f2_0, f2_1, f2_2, f2_3, s3_0, s3_1, s3_2, s3_3,
                   Bih3_h0, Bih3_h1, Bih3_l0, Bih3_l1,
                   Bhh3_h0, Bhh3_h1, Bhh3_l0, Bhh3_l1,
                   bias3, h3b[po], rowC0, jcol);
        __syncthreads();

        // Region B: fresh h1'(i) (doubles as next L1 state); L2(i); prefetch h3 state
        s1_0 = ldsA(h1b[pe], rowA, 0, g);  s1_1 = ldsA(h1b[pe], rowA, 1, g);
        s1_2 = ldsA(h1b[pe], rowA, 2, g);  s1_3 = ldsA(h1b[pe], rowA, 3, g);
        s3_0 = ldsA(h3b[po], rowA, 0, g);  s3_1 = ldsA(h3b[po], rowA, 1, g);
        s3_2 = ldsA(h3b[po], rowA, 2, g);  s3_3 = ldsA(h3b[po], rowA, 3, g);
        layer_full(s1_0, s1_1, s1_2, s1_3, f2_0, f2_1, f2_2, f2_3,
                   Bih2_h0, Bih2_h1, Bih2_l0, Bih2_l1,
                   Bhh2_h0, Bhh2_h1, Bhh2_l0, Bhh2_l1,
                   bias2, h2b[pe], rowC0, jcol);
        __syncthreads();
    }

    // ---- tail: L3(511) ----
    f2_0 = ldsA(h2b[1], rowA, 0, g);  f2_1 = ldsA(h2b[1], rowA, 1, g);
    f2_2 = ldsA(h2b[1], rowA, 2, g);  f2_3 = ldsA(h2b[1], rowA, 3, g);
    layer_full(f2_0, f2_1, f2_2, f2_3, s3_0, s3_1, s3_2, s3_3,
               Bih3_h0, Bih3_h1, Bih3_l0, Bih3_l1,
               Bhh3_h0, Bhh3_h1, Bhh3_l0, Bhh3_l1,
               bias3, h3b[1], rowC0, jcol);
    __syncthreads();

    // ---- FC epilogue from h3b[1] ----
    if (w == 0) {
        const short* h3f = h3b[1];
        int b = lane & 15, og = lane >> 4;
        for (int o = og; o < 10; o += 4) {
            float acc = bfc[o];
            for (int k = 0; k < 50; ++k)
                acc += (ldsR(h3f, b, k) + ldsR(h3f, b, 64 + k)) * Wfc[o * 50 + k];
            out[(size_t)(b0 + b) * 10 + o] = acc;
        }
    }
}

extern "C" void kernel_launch(void* const* d_in, const int* in_sizes, int n_in,
                              void* d_out, int out_size, void* d_ws, size_t ws_size,
                              hipStream_t stream) {
    const float* x    = (const float*)d_in[0];
    const float* Wih1 = (const float*)d_in[1];
    const float* Whh1 = (const float*)d_in[2];
    const float* bih1 = (const float*)d_in[3];
    const float* bhh1 = (const float*)d_in[4];
    const float* Wih2 = (const float*)d_in[5];
    const float* Whh2 = (const float*)d_in[6];
    const float* bih2 = (const float*)d_in[7];
    const float* bhh2 = (const float*)d_in[8];
    const float* Wih3 = (const float*)d_in[9];
    const float* Whh3 = (const float*)d_in[10];
    const float* bih3 = (const float*)d_in[11];
    const float* bhh3 = (const float*)d_in[12];
    const float* Wfc  = (const float*)d_in[13];
    const float* bfc  = (const float*)d_in[14];
    float* out = (float*)d_out;

    dim3 grid(256), block(256);
    hipLaunchKernelGGL(rnn3_kernel, grid, block, 0, stream,
                       x, Wih1, Whh1, bih1, bhh1,
                       Wih2, Whh2, bih2, bhh2,
                       Wih3, Whh3, bih3, bhh3,
                       Wfc, bfc, out);
}

// Round 5
// 439.955 us; speedup vs baseline: 1.1993x; 1.0545x over previous
//
#include <hip/hip_runtime.h>

typedef __attribute__((ext_vector_type(8))) short bf16x8;
typedef __attribute__((ext_vector_type(4))) float f32x4;

// Operand-swapped GEMM: D^T = W (A-operand) * h^T (B-operand).
// A-frag and B-frag layouts are mirror images (lane&15 indexes M-row / N-col,
// lane>>4 indexes the k-group), so fragments holding V[lane&15][(lane>>4)*8+i]
// serve as either operand. C-fragment holds 4 consecutive HIDDEN cols for one
// BATCH row -> contiguous b64 LDS writes in a [batch][hidden] layout.
#define MFMA(a, b, c) __builtin_amdgcn_mfma_f32_16x16x32_bf16((a), (b), (c), 0, 0, 0)

__device__ __forceinline__ short f2bf(float f) {
    union { float f; unsigned u; } v; v.f = f;
    unsigned r = v.u + 0x7fffu + ((v.u >> 16) & 1u);   // RNE
    return (short)(r >> 16);
}
__device__ __forceinline__ float bf2f(short h) {
    union { unsigned u; float f; } v;
    v.u = ((unsigned)(unsigned short)h) << 16;
    return v.f;
}
__device__ __forceinline__ void wsplit(float w, short& hi, short& lo) {
    hi = f2bf(w);
    lo = f2bf(w - bf2f(hi));
}
__device__ __forceinline__ float tanh_fast(float x) {
    float z = __builtin_amdgcn_exp2f(x * 2.8853900817779268f); // 2*log2(e)
    return 1.0f - 2.0f * __builtin_amdgcn_rcpf(z + 1.0f);
}
// packed bf16 convert: [15:0]=bf16(a), [31:16]=bf16(b). Pure VALU asm.
__device__ __forceinline__ unsigned cvt_pk_bf16(float a, float b) {
    unsigned r;
    asm("v_cvt_pk_bf16_f32 %0, %1, %2" : "=v"(r) : "v"(a), "v"(b));
    return r;
}

// weight fragment pair (hi + bf16 residual): element i = W[jrow][kbase+i], zero-padded
__device__ __forceinline__ void makeA2(const float* __restrict__ W, int jrow, int kbase,
                                       bf16x8& Ahi, bf16x8& Alo) {
#pragma unroll
    for (int i = 0; i < 8; ++i) {
        int m = kbase + i;
        short h = 0, l = 0;
        if (jrow < 50 && m < 50) wsplit(W[jrow * 50 + m], h, l);
        Ahi[i] = h; Alo[i] = l;
    }
}

// --- LDS h tile: [16 batch][128 hidden] bf16 (256B rows); cols 0-63 hi, 64-127 lo.
// XOR-swizzle bits 4-7 of the byte-in-row with the row index (bijective).
// NOTE: swz(row, b ^ 128) == swz(row, b) ^ 128 (bit 7 is in the XOR field) --
// the lo-half address must be derived by XOR, never by +128 (round-4 bug:
// for rows >= 8 the add carried into bit 8 = next row / out of bounds).
__device__ __forceinline__ int swz(int row, int byteInRow) {
    return (row << 8) + (byteInRow ^ ((row & 15) << 4));
}
__device__ __forceinline__ bf16x8 ldsA(const short* buf, int row, int kblk, int g) {
    return *(const bf16x8*)((const char*)buf + swz(row, (kblk << 6) + (g << 4)));
}
__device__ __forceinline__ float ldsR(const short* buf, int row, int col) {
    return bf2f(*(const short*)((const char*)buf + swz(row, col << 1)));
}

// store 4 consecutive hidden cols (hi + lo residual) for this lane's batch row.
// wb is the loop-invariant swizzled hi address; lo address = wb XOR 128.
__device__ __forceinline__ void storeT(char* wb, float t0, float t1, float t2, float t3) {
    unsigned h01 = cvt_pk_bf16(t0, t1);
    unsigned h23 = cvt_pk_bf16(t2, t3);
    float r0 = t0 - bf2f((short)h01);
    float r1 = t1 - bf2f((short)(h01 >> 16));
    float r2 = t2 - bf2f((short)h23);
    float r3 = t3 - bf2f((short)(h23 >> 16));
    unsigned l01 = cvt_pk_bf16(r0, r1);
    unsigned l23 = cvt_pk_bf16(r2, r3);
    uint2 hv; hv.x = h01; hv.y = h23;
    uint2 lv; lv.x = l01; lv.y = l23;
    *(uint2*)(wb) = hv;
    *(uint2*)((char*)((uintptr_t)wb ^ 128u)) = lv;
}

// full layer: ih on fwd input i*, hh on state s*. 12 MFMAs, 4 chains of 3.
__device__ __forceinline__ void layerT_full(
    const bf16x8& i0, const bf16x8& i1, const bf16x8& i2, const bf16x8& i3,
    const bf16x8& s0, const bf16x8& s1, const bf16x8& s2, const bf16x8& s3,
    const bf16x8& Ih0, const bf16x8& Ih1, const bf16x8& Il0, const bf16x8& Il1,
    const bf16x8& Hh0, const bf16x8& Hh1, const bf16x8& Hl0, const bf16x8& Hl1,
    const f32x4& cinit, char* wb)
{
    f32x4 z = {0.f, 0.f, 0.f, 0.f};
    f32x4 a0 = cinit, a1 = z, a2 = z, a3 = z;
    a0 = MFMA(Ih0, i0, a0);  a1 = MFMA(Hh0, s0, a1);
    a2 = MFMA(Ih0, i2, a2);  a3 = MFMA(Hh0, s2, a3);
    a0 = MFMA(Ih1, i1, a0);  a1 = MFMA(Hh1, s1, a1);
    a2 = MFMA(Ih1, i3, a2);  a3 = MFMA(Hh1, s3, a3);
    a0 = MFMA(Hl0, s0, a0);  a1 = MFMA(Il0, i0, a1);
    a2 = MFMA(Hl1, s1, a2);  a3 = MFMA(Il1, i1, a3);
    float t0 = tanh_fast(a0[0] + a1[0] + a2[0] + a3[0]);
    float t1 = tanh_fast(a0[1] + a1[1] + a2[1] + a3[1]);
    float t2 = tanh_fast(a0[2] + a1[2] + a2[2] + a3[2]);
    float t3 = tanh_fast(a0[3] + a1[3] + a2[3] + a3[3]);
    storeT(wb, t0, t1, t2, t3);
}

// single-matrix layer (L1 recurrence w/ x folded into cinit; also peel-B ih-only).
// 6 MFMAs, 3 chains of 2.
__device__ __forceinline__ void layerT_one(
    const bf16x8& s0, const bf16x8& s1, const bf16x8& s2, const bf16x8& s3,
    const bf16x8& Ah0, const bf16x8& Ah1, const bf16x8& Al0, const bf16x8& Al1,
    const f32x4& cinit, char* wb)
{
    f32x4 z = {0.f, 0.f, 0.f, 0.f};
    f32x4 a0 = cinit, a1 = z, a2 = z;
    a0 = MFMA(Ah0, s0, a0);  a1 = MFMA(Ah0, s2, a1);  a2 = MFMA(Al0, s0, a2);
    a0 = MFMA(Ah1, s1, a0);  a1 = MFMA(Ah1, s3, a1);  a2 = MFMA(Al1, s1, a2);
    float t0 = tanh_fast(a0[0] + a1[0] + a2[0]);
    float t1 = tanh_fast(a0[1] + a1[1] + a2[1]);
    float t2 = tanh_fast(a0[2] + a1[2] + a2[2]);
    float t3 = tanh_fast(a0[3] + a1[3] + a2[3]);
    storeT(wb, t0, t1, t2, t3);
}

__global__ __launch_bounds__(256, 1)
void rnn3_kernel(const float* __restrict__ x,
                 const float* __restrict__ Wih1, const float* __restrict__ Whh1,
                 const float* __restrict__ bih1, const float* __restrict__ bhh1,
                 const float* __restrict__ Wih2, const float* __restrict__ Whh2,
                 const float* __restrict__ bih2, const float* __restrict__ bhh2,
                 const float* __restrict__ Wih3, const float* __restrict__ Whh3,
                 const float* __restrict__ bih3, const float* __restrict__ bhh3,
                 const float* __restrict__ Wfc,  const float* __restrict__ bfc,
                 float* __restrict__ out)
{
    // single-buffered h state (hazards: each buffer written in one region,
    // read in the next, re-written a region later -> every boundary crosses a barrier)
    __shared__ __align__(16) short h1s[2048];
    __shared__ __align__(16) short h2s[2048];
    __shared__ __align__(16) short h3s[2048];
    __shared__ unsigned xp[512 * 16];   // x pre-split: lo16=x_hi(bf16), hi16=x_lo(bf16)

    const int tid  = threadIdx.x;
    const int lane = tid & 63;
    const int w    = tid >> 6;        // wave -> 16-row hidden stripe (M-tile)
    const int g    = lane >> 4;       // k-group
    const int l15  = lane & 15;
    const int jrow = (w << 4) | l15;  // A-frag hidden row (weight row)
    const int bcol = l15;             // B-frag / D batch row
    const int jout0 = (w << 4) + (g << 2);  // this lane's 4 output hidden cols
    const int b0   = blockIdx.x * 16;

    // ---- stage x, pre-split into bf16 hi/lo ----
    {
        const float4* xg = (const float4*)(x + (size_t)b0 * 512);
        for (int idx = tid; idx < 2048; idx += 256) {
            float4 v = xg[idx];
            int b = idx >> 7, t0 = (idx & 127) << 2;
            float vv[4] = {v.x, v.y, v.z, v.w};
#pragma unroll
            for (int j = 0; j < 4; ++j) {
                short h, l; wsplit(vv[j], h, l);
                xp[(t0 + j) * 16 + b] = (unsigned)(unsigned short)h
                                      | ((unsigned)(unsigned short)l << 16);
            }
        }
    }

    // ---- persistent weight fragments (A-operand; hi + lo residual) ----
    const int k8 = g << 3;
    bf16x8 A1h0, A1l0, A1h1, A1l1;
    makeA2(Whh1, jrow, k8,      A1h0, A1l0);
    makeA2(Whh1, jrow, 32 + k8, A1h1, A1l1);
    bf16x8 I2h0, I2l0, I2h1, I2l1;
    makeA2(Wih2, jrow, k8,      I2h0, I2l0);
    makeA2(Wih2, jrow, 32 + k8, I2h1, I2l1);
    bf16x8 H2h0, H2l0, H2h1, H2l1;
    makeA2(Whh2, jrow, k8,      H2h0, H2l0);
    makeA2(Whh2, jrow, 32 + k8, H2h1, H2l1);
    bf16x8 I3h0, I3l0, I3h1, I3l1;
    makeA2(Wih3, jrow, k8,      I3h0, I3l0);
    makeA2(Wih3, jrow, 32 + k8, I3h1, I3l1);
    bf16x8 H3h0, H3l0, H3h1, H3l1;
    makeA2(Whh3, jrow, k8,      H3h0, H3l0);
    makeA2(Whh3, jrow, 32 + k8, H3h1, H3l1);

    // per-lane biases for its 4 output hidden cols + fp32 Wih1 for the x fold
    f32x4 b1v, b2v, b3v, w1f;
#pragma unroll
    for (int r = 0; r < 4; ++r) {
        int j = jout0 + r;
        bool v = j < 50;
        b1v[r] = v ? (bih1[j] + bhh1[j]) : 0.0f;
        b2v[r] = v ? (bih2[j] + bhh2[j]) : 0.0f;
        b3v[r] = v ? (bih3[j] + bhh3[j]) : 0.0f;
        w1f[r] = v ? Wih1[j] : 0.0f;
    }

    // loop-invariant swizzled LDS write addresses (hi half; lo = XOR 128)
    const int wbyte = swz(bcol, jout0 << 1);
    char* wb1 = (char*)h1s + wbyte;
    char* wb2 = (char*)h2s + wbyte;
    char* wb3 = (char*)h3s + wbyte;

    __syncthreads();   // x staged

    // register-held states (zero = h(-1))
    bf16x8 zf = {0,0,0,0,0,0,0,0};
    bf16x8 s1_0 = zf, s1_1 = zf, s1_2 = zf, s1_3 = zf; // h1 state (B-frags)
    bf16x8 f2_0 = zf, f2_1 = zf, f2_2 = zf, f2_3 = zf; // h2 state / fwd
    bf16x8 s3_0 = zf, s3_1 = zf, s3_2 = zf, s3_3 = zf; // h3 state

    // ---- peel t=0.  A: L1(0) (states zero -> pure scalar)  B: L2(0) (ih-only) ----
    {
        unsigned xw = xp[bcol];
        float xf = bf2f((short)xw) + bf2f((short)(xw >> 16));
        float t0 = tanh_fast(fmaf(w1f[0], xf, b1v[0]));
        float t1 = tanh_fast(fmaf(w1f[1], xf, b1v[1]));
        float t2 = tanh_fast(fmaf(w1f[2], xf, b1v[2]));
        float t3 = tanh_fast(fmaf(w1f[3], xf, b1v[3]));
        storeT(wb1, t0, t1, t2, t3);
        __syncthreads();
        s1_0 = ldsA(h1s, bcol, 0, g);  s1_1 = ldsA(h1s, bcol, 1, g);
        s1_2 = ldsA(h1s, bcol, 2, g);  s1_3 = ldsA(h1s, bcol, 3, g);
        layerT_one(s1_0, s1_1, s1_2, s1_3, I2h0, I2h1, I2l0, I2l1, b2v, wb2);
        __syncthreads();
    }

    // ---- main loop:  A = {L1(i), L3(i-1)}  bar  B = {L2(i)}  bar ----
    for (int i = 1; i < 512; ++i) {
        // Region A: fresh h2(i-1); L1 on reg state; L3 on fresh h2 + reg h3 state
        f2_0 = ldsA(h2s, bcol, 0, g);  f2_1 = ldsA(h2s, bcol, 1, g);
        f2_2 = ldsA(h2s, bcol, 2, g);  f2_3 = ldsA(h2s, bcol, 3, g);
        unsigned xw = xp[i * 16 + bcol];
        float xf = bf2f((short)xw) + bf2f((short)(xw >> 16));
        f32x4 c1i;
        c1i[0] = fmaf(w1f[0], xf, b1v[0]);
        c1i[1] = fmaf(w1f[1], xf, b1v[1]);
        c1i[2] = fmaf(w1f[2], xf, b1v[2]);
        c1i[3] = fmaf(w1f[3], xf, b1v[3]);
        layerT_one(s1_0, s1_1, s1_2, s1_3, A1h0, A1h1, A1l0, A1l1, c1i, wb1);
        layerT_full(f2_0, f2_1, f2_2, f2_3, s3_0, s3_1, s3_2, s3_3,
                    I3h0, I3h1, I3l0, I3l1, H3h0, H3h1, H3l0, H3l1, b3v, wb3);
        __syncthreads();

        // Region B: fresh h1(i) (doubles as next L1 state); prefetch h3(i-1); L2(i)
        s1_0 = ldsA(h1s, bcol, 0, g);  s1_1 = ldsA(h1s, bcol, 1, g);
        s1_2 = ldsA(h1s, bcol, 2, g);  s1_3 = ldsA(h1s, bcol, 3, g);
        s3_0 = ldsA(h3s, bcol, 0, g);  s3_1 = ldsA(h3s, bcol, 1, g);
        s3_2 = ldsA(h3s, bcol, 2, g);  s3_3 = ldsA(h3s, bcol, 3, g);
        layerT_full(s1_0, s1_1, s1_2, s1_3, f2_0, f2_1, f2_2, f2_3,
                    I2h0, I2h1, I2l0, I2l1, H2h0, H2h1, H2l0, H2l1, b2v, wb2);
        __syncthreads();
    }

    // ---- tail: L3(511) ----
    f2_0 = ldsA(h2s, bcol, 0, g);  f2_1 = ldsA(h2s, bcol, 1, g);
    f2_2 = ldsA(h2s, bcol, 2, g);  f2_3 = ldsA(h2s, bcol, 3, g);
    layerT_full(f2_0, f2_1, f2_2, f2_3, s3_0, s3_1, s3_2, s3_3,
                I3h0, I3h1, I3l0, I3l1, H3h0, H3h1, H3l0, H3l1, b3v, wb3);
    __syncthreads();

    // ---- FC epilogue: out[b][o] = (h3_hi + h3_lo) @ Wfc^T + bfc ----
    {
        int o = (w << 2) | g;           // 0..15, valid < 10
        int b = bcol;
        if (o < 10) {
            float acc = bfc[o];
            for (int k = 0; k < 50; ++k)
                acc += (ldsR(h3s, b, k) + ldsR(h3s, b, 64 + k)) * Wfc[o * 50 + k];
            out[(size_t)(b0 + b) * 10 + o] = acc;
        }
    }
}

extern "C" void kernel_launch(void* const* d_in, const int* in_sizes, int n_in,
                              void* d_out, int out_size, void* d_ws, size_t ws_size,
                              hipStream_t stream) {
    const float* x    = (const float*)d_in[0];
    const float* Wih1 = (const float*)d_in[1];
    const float* Whh1 = (const float*)d_in[2];
    const float* bih1 = (const float*)d_in[3];
    const float* bhh1 = (const float*)d_in[4];
    const float* Wih2 = (const float*)d_in[5];
    const float* Whh2 = (const float*)d_in[6];
    const float* bih2 = (const float*)d_in[7];
    const float* bhh2 = (const float*)d_in[8];
    const float* Wih3 = (const float*)d_in[9];
    const float* Whh3 = (const float*)d_in[10];
    const float* bih3 = (const float*)d_in[11];
    const float* bhh3 = (const float*)d_in[12];
    const float* Wfc  = (const float*)d_in[13];
    const float* bfc  = (const float*)d_in[14];
    float* out = (float*)d_out;

    dim3 grid(256), block(256);
    hipLaunchKernelGGL(rnn3_kernel, grid, block, 0, stream,
                       x, Wih1, Whh1, bih1, bhh1,
                       Wih2, Whh2, bih2, bhh2,
                       Wih3, Whh3, bih3, bhh3,
                       Wfc, bfc, out);
}

// Round 7
// 402.287 us; speedup vs baseline: 1.3116x; 1.0936x over previous
//
#include <hip/hip_runtime.h>

typedef __attribute__((ext_vector_type(8))) short bf16x8;
typedef __attribute__((ext_vector_type(4))) float f32x4;

// Operand-swapped GEMM: D^T = W (A-operand) * h^T (B-operand).
// C-fragment holds 4 consecutive HIDDEN cols for one BATCH row -> contiguous
// b64 LDS writes (hi at off, lo at off XOR 128) in a [batch][hidden] layout.
#define MFMA(a, b, c) __builtin_amdgcn_mfma_f32_16x16x32_bf16((a), (b), (c), 0, 0, 0)

__device__ __forceinline__ short f2bf(float f) {
    union { float f; unsigned u; } v; v.f = f;
    unsigned r = v.u + 0x7fffu + ((v.u >> 16) & 1u);   // RNE
    return (short)(r >> 16);
}
__device__ __forceinline__ float bf2f(short h) {
    union { unsigned u; float f; } v;
    v.u = ((unsigned)(unsigned short)h) << 16;
    return v.f;
}
__device__ __forceinline__ void wsplit(float w, short& hi, short& lo) {
    hi = f2bf(w);
    lo = f2bf(w - bf2f(hi));
}
__device__ __forceinline__ float tanh_fast(float x) {
    float z = __builtin_amdgcn_exp2f(x * 2.8853900817779268f); // 2*log2(e)
    return 1.0f - 2.0f * __builtin_amdgcn_rcpf(z + 1.0f);
}
__device__ __forceinline__ unsigned cvt_pk_bf16(float a, float b) {
    unsigned r;
    asm("v_cvt_pk_bf16_f32 %0, %1, %2" : "=v"(r) : "v"(a), "v"(b));
    return r;
}

// weight fragment pair (hi + bf16 residual): element i = W[jrow][kbase+i], zero-padded
__device__ __forceinline__ void makeA2(const float* __restrict__ W, int jrow, int kbase,
                                       bf16x8& Ahi, bf16x8& Alo) {
#pragma unroll
    for (int i = 0; i < 8; ++i) {
        int m = kbase + i;
        short h = 0, l = 0;
        if (jrow < 50 && m < 50) wsplit(W[jrow * 50 + m], h, l);
        Ahi[i] = h; Alo[i] = l;
    }
}

// --- LDS h tile: [16 batch][128 hidden] bf16 (256B rows); cols 0-63 hi, 64-127 lo.
// XOR-swizzle bits 4-7 of byte-in-row with row (bijective).
// swz(row, b ^ 128) == swz(row, b) ^ 128 -> lo offset derived by XOR on the
// INTEGER offset (never +128, never XOR on a flat pointer).
__device__ __forceinline__ int swz(int row, int byteInRow) {
    return (row << 8) + (byteInRow ^ ((row & 15) << 4));
}
__device__ __forceinline__ bf16x8 ldsA(const short* buf, int row, int kblk, int g) {
    return *(const bf16x8*)((const char*)buf + swz(row, (kblk << 6) + (g << 4)));
}
__device__ __forceinline__ float ldsR(const short* buf, int row, int col) {
    return bf2f(*(const short*)((const char*)buf + swz(row, col << 1)));
}

// store 4 consecutive hidden cols (hi + lo residual) for this lane's batch row.
__device__ __forceinline__ void storeT(short* buf, int off, float t0, float t1, float t2, float t3) {
    unsigned h01 = cvt_pk_bf16(t0, t1);
    unsigned h23 = cvt_pk_bf16(t2, t3);
    float r0 = t0 - bf2f((short)h01);
    float r1 = t1 - bf2f((short)(h01 >> 16));
    float r2 = t2 - bf2f((short)h23);
    float r3 = t3 - bf2f((short)(h23 >> 16));
    unsigned l01 = cvt_pk_bf16(r0, r1);
    unsigned l23 = cvt_pk_bf16(r2, r3);
    uint2 hv; hv.x = h01; hv.y = h23;
    uint2 lv; lv.x = l01; lv.y = l23;
    *(uint2*)((char*)buf + off)         = hv;
    *(uint2*)((char*)buf + (off ^ 128)) = lv;
}

// full layer: ih on fwd input i*, hh on state s*. 12 MFMAs, 4 chains of 3.
__device__ __forceinline__ void layerT_full(
    const bf16x8& i0, const bf16x8& i1, const bf16x8& i2, const bf16x8& i3,
    const bf16x8& s0, const bf16x8& s1, const bf16x8& s2, const bf16x8& s3,
    const bf16x8& Ih0, const bf16x8& Ih1, const bf16x8& Il0, const bf16x8& Il1,
    const bf16x8& Hh0, const bf16x8& Hh1, const bf16x8& Hl0, const bf16x8& Hl1,
    const f32x4& cinit, short* wbuf, int off)
{
    f32x4 z = {0.f, 0.f, 0.f, 0.f};
    f32x4 a0 = cinit, a1 = z, a2 = z, a3 = z;
    a0 = MFMA(Ih0, i0, a0);  a1 = MFMA(Hh0, s0, a1);
    a2 = MFMA(Ih0, i2, a2);  a3 = MFMA(Hh0, s2, a3);
    a0 = MFMA(Ih1, i1, a0);  a1 = MFMA(Hh1, s1, a1);
    a2 = MFMA(Ih1, i3, a2);  a3 = MFMA(Hh1, s3, a3);
    a0 = MFMA(Hl0, s0, a0);  a1 = MFMA(Il0, i0, a1);
    a2 = MFMA(Hl1, s1, a2);  a3 = MFMA(Il1, i1, a3);
    float t0 = tanh_fast(a0[0] + a1[0] + a2[0] + a3[0]);
    float t1 = tanh_fast(a0[1] + a1[1] + a2[1] + a3[1]);
    float t2 = tanh_fast(a0[2] + a1[2] + a2[2] + a3[2]);
    float t3 = tanh_fast(a0[3] + a1[3] + a2[3] + a3[3]);
    storeT(wbuf, off, t0, t1, t2, t3);
}

// single-matrix layer (hi/lo of one matrix on one input): 6 MFMAs, 3 chains of 2.
__device__ __forceinline__ void layerT_one(
    const bf16x8& s0, const bf16x8& s1, const bf16x8& s2, const bf16x8& s3,
    const bf16x8& Ah0, const bf16x8& Ah1, const bf16x8& Al0, const bf16x8& Al1,
    const f32x4& cinit, short* wbuf, int off)
{
    f32x4 z = {0.f, 0.f, 0.f, 0.f};
    f32x4 a0 = cinit, a1 = z, a2 = z;
    a0 = MFMA(Ah0, s0, a0);  a1 = MFMA(Ah0, s2, a1);  a2 = MFMA(Al0, s0, a2);
    a0 = MFMA(Ah1, s1, a0);  a1 = MFMA(Ah1, s3, a1);  a2 = MFMA(Al1, s1, a2);
    float t0 = tanh_fast(a0[0] + a1[0] + a2[0]);
    float t1 = tanh_fast(a0[1] + a1[1] + a2[1]);
    float t2 = tanh_fast(a0[2] + a1[2] + a2[2]);
    float t3 = tanh_fast(a0[3] + a1[3] + a2[3]);
    storeT(wbuf, off, t0, t1, t2, t3);
}

// one pipeline phase: reads r1/r2/r3 (prev parity), writes w1/w2/w3 (this parity).
// Mid-phase barrier guarantees ALL reads complete chip-wide before ANY write.
__device__ __forceinline__ void phaseT(
    const short* r1, const short* r2, const short* r3,
    short* w1, short* w2, short* w3,
    int bcol, int g, int wbyte, float xf,
    const f32x4& b1v, const f32x4& b2v, const f32x4& b3v, const f32x4& w1f,
    const bf16x8& A1h0, const bf16x8& A1h1, const bf16x8& A1l0, const bf16x8& A1l1,
    const bf16x8& I2h0, const bf16x8& I2h1, const bf16x8& I2l0, const bf16x8& I2l1,
    const bf16x8& H2h0, const bf16x8& H2h1, const bf16x8& H2l0, const bf16x8& H2l1,
    const bf16x8& I3h0, const bf16x8& I3h1, const bf16x8& I3l0, const bf16x8& I3l1,
    const bf16x8& H3h0, const bf16x8& H3h1, const bf16x8& H3l0, const bf16x8& H3l1)
{
    bf16x8 s1_0 = ldsA(r1, bcol, 0, g), s1_1 = ldsA(r1, bcol, 1, g);
    bf16x8 s1_2 = ldsA(r1, bcol, 2, g), s1_3 = ldsA(r1, bcol, 3, g);
    bf16x8 f2_0 = ldsA(r2, bcol, 0, g), f2_1 = ldsA(r2, bcol, 1, g);
    bf16x8 f2_2 = ldsA(r2, bcol, 2, g), f2_3 = ldsA(r2, bcol, 3, g);
    bf16x8 s3_0 = ldsA(r3, bcol, 0, g), s3_1 = ldsA(r3, bcol, 1, g);
    bf16x8 s3_2 = ldsA(r3, bcol, 2, g), s3_3 = ldsA(r3, bcol, 3, g);
    __syncthreads();   // containment: reads drained before any write this phase
    f32x4 c1i;
    c1i[0] = fmaf(w1f[0], xf, b1v[0]);
    c1i[1] = fmaf(w1f[1], xf, b1v[1]);
    c1i[2] = fmaf(w1f[2], xf, b1v[2]);
    c1i[3] = fmaf(w1f[3], xf, b1v[3]);
    // L2(i-1): input h1(i-1)=s1, state h2(i-2)=f2
    layerT_full(s1_0, s1_1, s1_2, s1_3, f2_0, f2_1, f2_2, f2_3,
                I2h0, I2h1, I2l0, I2l1, H2h0, H2h1, H2l0, H2l1, b2v, w2, wbyte);
    // L3(i-2): input h2(i-2)=f2, state h3(i-3)=s3
    layerT_full(f2_0, f2_1, f2_2, f2_3, s3_0, s3_1, s3_2, s3_3,
                I3h0, I3h1, I3l0, I3l1, H3h0, H3h1, H3l0, H3l1, b3v, w3, wbyte);
    // L1(i): state h1(i-1)=s1, x folded into cinit
    layerT_one(s1_0, s1_1, s1_2, s1_3, A1h0, A1h1, A1l0, A1l1, c1i, w1, wbyte);
    __syncthreads();
}

__global__ __launch_bounds__(256, 1)
void rnn3_kernel(const float* __restrict__ x,
                 const float* __restrict__ Wih1, const float* __restrict__ Whh1,
                 const float* __restrict__ bih1, const float* __restrict__ bhh1,
                 const float* __restrict__ Wih2, const float* __restrict__ Whh2,
                 const float* __restrict__ bih2, const float* __restrict__ bhh2,
                 const float* __restrict__ Wih3, const float* __restrict__ Whh3,
                 const float* __restrict__ bih3, const float* __restrict__ bhh3,
                 const float* __restrict__ Wfc,  const float* __restrict__ bfc,
                 float* __restrict__ out)
{
    __shared__ __align__(16) short h1s[2][2048];
    __shared__ __align__(16) short h2s[2][2048];
    __shared__ __align__(16) short h3s[2][2048];
    __shared__ float xls[512 * 17 + 32];   // x as f32, stride-17 pad

    const int tid  = threadIdx.x;
    const int lane = tid & 63;
    const int w    = tid >> 6;
    const int g    = lane >> 4;
    const int l15  = lane & 15;
    const int jrow = (w << 4) | l15;        // A-frag weight row
    const int bcol = l15;                   // B-frag / D batch row
    const int jout0 = (w << 4) + (g << 2);  // lane's 4 output hidden cols
    const int b0   = blockIdx.x * 16;

    // ---- zero-init ALL h buffers (uninit reads become 0, never NaN) ----
    { int* z1 = (int*)h1s; int* z2 = (int*)h2s; int* z3 = (int*)h3s;
      for (int k = tid; k < 2048; k += 256) { z1[k] = 0; z2[k] = 0; z3[k] = 0; } }

    // ---- stage x as f32 [t][b] (stride 17) ----
    {
        const float4* xg = (const float4*)(x + (size_t)b0 * 512);
        for (int idx = tid; idx < 2048; idx += 256) {   // 16 rows * 128 float4
            float4 v = xg[idx];
            int b = idx >> 7, t0 = (idx & 127) << 2;
            xls[(t0 + 0) * 17 + b] = v.x;
            xls[(t0 + 1) * 17 + b] = v.y;
            xls[(t0 + 2) * 17 + b] = v.z;
            xls[(t0 + 3) * 17 + b] = v.w;
        }
    }

    // ---- persistent weight fragments (hi + lo residual) ----
    const int k8 = g << 3;
    bf16x8 A1h0, A1l0, A1h1, A1l1;
    makeA2(Whh1, jrow, k8,      A1h0, A1l0);
    makeA2(Whh1, jrow, 32 + k8, A1h1, A1l1);
    bf16x8 I2h0, I2l0, I2h1, I2l1;
    makeA2(Wih2, jrow, k8,      I2h0, I2l0);
    makeA2(Wih2, jrow, 32 + k8, I2h1, I2l1);
    bf16x8 H2h0, H2l0, H2h1, H2l1;
    makeA2(Whh2, jrow, k8,      H2h0, H2l0);
    makeA2(Whh2, jrow, 32 + k8, H2h1, H2l1);
    bf16x8 I3h0, I3l0, I3h1, I3l1;
    makeA2(Wih3, jrow, k8,      I3h0, I3l0);
    makeA2(Wih3, jrow, 32 + k8, I3h1, I3l1);
    bf16x8 H3h0, H3l0, H3h1, H3l1;
    makeA2(Whh3, jrow, k8,      H3h0, H3l0);
    makeA2(Whh3, jrow, 32 + k8, H3h1, H3l1);

    f32x4 b1v, b2v, b3v, w1f;
#pragma unroll
    for (int r = 0; r < 4; ++r) {
        int j = jout0 + r;
        bool v = j < 50;
        b1v[r] = v ? (bih1[j] + bhh1[j]) : 0.0f;
        b2v[r] = v ? (bih2[j] + bhh2[j]) : 0.0f;
        b3v[r] = v ? (bih3[j] + bhh3[j]) : 0.0f;
        w1f[r] = v ? Wih1[j] : 0.0f;
    }

    const int wbyte = swz(bcol, jout0 << 1);

    __syncthreads();   // x staged, h buffers zeroed

    // ---- phase 0: L1(0) (all states zero -> pure scalar path) -> h1[0] ----
    {
        float xf = xls[bcol];
        float t0 = tanh_fast(fmaf(w1f[0], xf, b1v[0]));
        float t1 = tanh_fast(fmaf(w1f[1], xf, b1v[1]));
        float t2 = tanh_fast(fmaf(w1f[2], xf, b1v[2]));
        float t3 = tanh_fast(fmaf(w1f[3], xf, b1v[3]));
        storeT(h1s[0], wbyte, t0, t1, t2, t3);
        __syncthreads();
    }
    // ---- phase 1: L1(1) -> h1[1], L2(0) (ih-only) -> h2[1] ----
    {
        bf16x8 s1_0 = ldsA(h1s[0], bcol, 0, g), s1_1 = ldsA(h1s[0], bcol, 1, g);
        bf16x8 s1_2 = ldsA(h1s[0], bcol, 2, g), s1_3 = ldsA(h1s[0], bcol, 3, g);
        float xf = xls[17 + bcol];
        f32x4 c1i;
        c1i[0] = fmaf(w1f[0], xf, b1v[0]);
        c1i[1] = fmaf(w1f[1], xf, b1v[1]);
        c1i[2] = fmaf(w1f[2], xf, b1v[2]);
        c1i[3] = fmaf(w1f[3], xf, b1v[3]);
        layerT_one(s1_0, s1_1, s1_2, s1_3, I2h0, I2h1, I2l0, I2l1, b2v, h2s[1], wbyte);
        layerT_one(s1_0, s1_1, s1_2, s1_3, A1h0, A1h1, A1l0, A1l1, c1i, h1s[1], wbyte);
        __syncthreads();
    }

    // ---- main phases i=2..511 (manual 2x unroll, compile-time parities) ----
    for (int i = 2; i < 512; i += 2) {
        // even phase: read parity 1, write parity 0
        phaseT(h1s[1], h2s[1], h3s[1], h1s[0], h2s[0], h3s[0],
               bcol, g, wbyte, xls[i * 17 + bcol],
               b1v, b2v, b3v, w1f,
               A1h0, A1h1, A1l0, A1l1,
               I2h0, I2h1, I2l0, I2l1, H2h0, H2h1, H2l0, H2l1,
               I3h0, I3h1, I3l0, I3l1, H3h0, H3h1, H3l0, H3l1);
        // odd phase: read parity 0, write parity 1
        phaseT(h1s[0], h2s[0], h3s[0], h1s[1], h2s[1], h3s[1],
               bcol, g, wbyte, xls[(i + 1) * 17 + bcol],
               b1v, b2v, b3v, w1f,
               A1h0, A1h1, A1l0, A1l1,
               I2h0, I2h1, I2l0, I2l1, H2h0, H2h1, H2l0, H2l1,
               I3h0, I3h1, I3l0, I3l1, H3h0, H3h1, H3l0, H3l1);
    }

    // ---- phase 512: L2(511) -> h2[0], L3(510) -> h3[0] ----
    {
        bf16x8 s1_0 = ldsA(h1s[1], bcol, 0, g), s1_1 = ldsA(h1s[1], bcol, 1, g);
        bf16x8 s1_2 = ldsA(h1s[1], bcol, 2, g), s1_3 = ldsA(h1s[1], bcol, 3, g);
        bf16x8 f2_0 = ldsA(h2s[1], bcol, 0, g), f2_1 = ldsA(h2s[1], bcol, 1, g);
        bf16x8 f2_2 = ldsA(h2s[1], bcol, 2, g), f2_3 = ldsA(h2s[1], bcol, 3, g);
        bf16x8 s3_0 = ldsA(h3s[1], bcol, 0, g), s3_1 = ldsA(h3s[1], bcol, 1, g);
        bf16x8 s3_2 = ldsA(h3s[1], bcol, 2, g), s3_3 = ldsA(h3s[1], bcol, 3, g);
        __syncthreads();
        layerT_full(s1_0, s1_1, s1_2, s1_3, f2_0, f2_1, f2_2, f2_3,
                    I2h0, I2h1, I2l0, I2l1, H2h0, H2h1, H2l0, H2l1,
                    b2v, h2s[0], wbyte);
        layerT_full(f2_0, f2_1, f2_2, f2_3, s3_0, s3_1, s3_2, s3_3,
                    I3h0, I3h1, I3l0, I3l1, H3h0, H3h1, H3l0, H3l1,
                    b3v, h3s[0], wbyte);
        __syncthreads();
    }
    // ---- phase 513: L3(511) -> h3[1] ----
    {
        bf16x8 f2_0 = ldsA(h2s[0], bcol, 0, g), f2_1 = ldsA(h2s[0], bcol, 1, g);
        bf16x8 f2_2 = ldsA(h2s[0], bcol, 2, g), f2_3 = ldsA(h2s[0], bcol, 3, g);
        bf16x8 s3_0 = ldsA(h3s[0], bcol, 0, g), s3_1 = ldsA(h3s[0], bcol, 1, g);
        bf16x8 s3_2 = ldsA(h3s[0], bcol, 2, g), s3_3 = ldsA(h3s[0], bcol, 3, g);
        __syncthreads();
        layerT_full(f2_0, f2_1, f2_2, f2_3, s3_0, s3_1, s3_2, s3_3,
                    I3h0, I3h1, I3l0, I3l1, H3h0, H3h1, H3l0, H3l1,
                    b3v, h3s[1], wbyte);
        __syncthreads();
    }

    // ---- FC epilogue: out[b][o] = (h3_hi + h3_lo) @ Wfc^T + bfc ----
    {
        const short* h3f = h3s[1];
        int o = (w << 2) | g;           // 0..15, valid < 10
        int b = bcol;
        if (o < 10) {
            float acc = bfc[o];
            for (int k = 0; k < 50; ++k)
                acc += (ldsR(h3f, b, k) + ldsR(h3f, b, 64 + k)) * Wfc[o * 50 + k];
            out[(size_t)(b0 + b) * 10 + o] = acc;
        }
    }
}

extern "C" void kernel_launch(void* const* d_in, const int* in_sizes, int n_in,
                              void* d_out, int out_size, void* d_ws, size_t ws_size,
                              hipStream_t stream) {
    const float* x    = (const float*)d_in[0];
    const float* Wih1 = (const float*)d_in[1];
    const float* Whh1 = (const float*)d_in[2];
    const float* bih1 = (const float*)d_in[3];
    const float* bhh1 = (const float*)d_in[4];
    const float* Wih2 = (const float*)d_in[5];
    const float* Whh2 = (const float*)d_in[6];
    const float* bih2 = (const float*)d_in[7];
    const float* bhh2 = (const float*)d_in[8];
    const float* Wih3 = (const float*)d_in[9];
    const float* Whh3 = (const float*)d_in[10];
    const float* bih3 = (const float*)d_in[11];
    const float* bhh3 = (const float*)d_in[12];
    const float* Wfc  = (const float*)d_in[13];
    const float* bfc  = (const float*)d_in[14];
    float* out = (float*)d_out;

    dim3 grid(256), block(256);
    hipLaunchKernelGGL(rnn3_kernel, grid, block, 0, stream,
                       x, Wih1, Whh1, bih1, bhh1,
                       Wih2, Whh2, bih2, bhh2,
                       Wih3, Whh3, bih3, bhh3,
                       Wfc, bfc, out);
}

// Round 8
// 380.993 us; speedup vs baseline: 1.3849x; 1.0559x over previous
//
#include <hip/hip_runtime.h>

typedef __attribute__((ext_vector_type(8))) short bf16x8;
typedef __attribute__((ext_vector_type(4))) float f32x4;

// Operand-swapped GEMM: D^T = W (A-operand) * h^T (B-operand).
// C-fragment holds 4 consecutive HIDDEN cols for one BATCH row -> contiguous
// b64 LDS writes (hi at off, lo at off XOR 128) in a [batch][hidden] layout.
#define MFMA(a, b, c) __builtin_amdgcn_mfma_f32_16x16x32_bf16((a), (b), (c), 0, 0, 0)

__device__ __forceinline__ short f2bf(float f) {
    union { float f; unsigned u; } v; v.f = f;
    unsigned r = v.u + 0x7fffu + ((v.u >> 16) & 1u);   // RNE
    return (short)(r >> 16);
}
__device__ __forceinline__ float bf2f(short h) {
    union { unsigned u; float f; } v;
    v.u = ((unsigned)(unsigned short)h) << 16;
    return v.f;
}
__device__ __forceinline__ void wsplit(float w, short& hi, short& lo) {
    hi = f2bf(w);
    lo = f2bf(w - bf2f(hi));
}
__device__ __forceinline__ float tanh_fast(float x) {
    float z = __builtin_amdgcn_exp2f(x * 2.8853900817779268f); // 2*log2(e)
    return 1.0f - 2.0f * __builtin_amdgcn_rcpf(z + 1.0f);
}
__device__ __forceinline__ unsigned cvt_pk_bf16(float a, float b) {
    unsigned r;
    asm("v_cvt_pk_bf16_f32 %0, %1, %2" : "=v"(r) : "v"(a), "v"(b));
    return r;
}

// weight fragment pair (hi + bf16 residual): element i = W[jrow][kbase+i], zero-padded
__device__ __forceinline__ void makeA2(const float* __restrict__ W, int jrow, int kbase,
                                       bf16x8& Ahi, bf16x8& Alo) {
#pragma unroll
    for (int i = 0; i < 8; ++i) {
        int m = kbase + i;
        short h = 0, l = 0;
        if (jrow < 50 && m < 50) wsplit(W[jrow * 50 + m], h, l);
        Ahi[i] = h; Alo[i] = l;
    }
}

// --- LDS h tile: [16 batch][128 hidden] bf16 (256B rows); cols 0-63 hi, 64-127 lo.
// XOR-swizzle bits 4-7 of byte-in-row with row (bijective).
// swz(row, b ^ 128) == swz(row, b) ^ 128 -> lo offset derived by XOR on the
// INTEGER offset (never +128, never XOR on a flat pointer).
__device__ __forceinline__ int swz(int row, int byteInRow) {
    return (row << 8) + (byteInRow ^ ((row & 15) << 4));
}
__device__ __forceinline__ bf16x8 ldsA(const short* buf, int row, int kblk, int g) {
    return *(const bf16x8*)((const char*)buf + swz(row, (kblk << 6) + (g << 4)));
}
__device__ __forceinline__ float ldsR(const short* buf, int row, int col) {
    return bf2f(*(const short*)((const char*)buf + swz(row, col << 1)));
}

// store 4 consecutive hidden cols (hi + lo residual) for this lane's batch row.
__device__ __forceinline__ void storeT(short* buf, int off, float t0, float t1, float t2, float t3) {
    unsigned h01 = cvt_pk_bf16(t0, t1);
    unsigned h23 = cvt_pk_bf16(t2, t3);
    float r0 = t0 - bf2f((short)h01);
    float r1 = t1 - bf2f((short)(h01 >> 16));
    float r2 = t2 - bf2f((short)h23);
    float r3 = t3 - bf2f((short)(h23 >> 16));
    unsigned l01 = cvt_pk_bf16(r0, r1);
    unsigned l23 = cvt_pk_bf16(r2, r3);
    uint2 hv; hv.x = h01; hv.y = h23;
    uint2 lv; lv.x = l01; lv.y = l23;
    *(uint2*)((char*)buf + off)         = hv;
    *(uint2*)((char*)buf + (off ^ 128)) = lv;
}

// full layer (helper for peel/drain only): 12 MFMAs, 4 chains of 3.
__device__ __forceinline__ void layerT_full(
    const bf16x8& i0, const bf16x8& i1, const bf16x8& i2, const bf16x8& i3,
    const bf16x8& s0, const bf16x8& s1, const bf16x8& s2, const bf16x8& s3,
    const bf16x8& Ih0, const bf16x8& Ih1, const bf16x8& Il0, const bf16x8& Il1,
    const bf16x8& Hh0, const bf16x8& Hh1, const bf16x8& Hl0, const bf16x8& Hl1,
    const f32x4& cinit, short* wbuf, int off)
{
    f32x4 z = {0.f, 0.f, 0.f, 0.f};
    f32x4 a0 = cinit, a1 = z, a2 = z, a3 = z;
    a0 = MFMA(Ih0, i0, a0);  a1 = MFMA(Hh0, s0, a1);
    a2 = MFMA(Ih0, i2, a2);  a3 = MFMA(Hh0, s2, a3);
    a0 = MFMA(Ih1, i1, a0);  a1 = MFMA(Hh1, s1, a1);
    a2 = MFMA(Ih1, i3, a2);  a3 = MFMA(Hh1, s3, a3);
    a0 = MFMA(Hl0, s0, a0);  a1 = MFMA(Il0, i0, a1);
    a2 = MFMA(Hl1, s1, a2);  a3 = MFMA(Il1, i1, a3);
    float t0 = tanh_fast(a0[0] + a1[0] + a2[0] + a3[0]);
    float t1 = tanh_fast(a0[1] + a1[1] + a2[1] + a3[1]);
    float t2 = tanh_fast(a0[2] + a1[2] + a2[2] + a3[2]);
    float t3 = tanh_fast(a0[3] + a1[3] + a2[3] + a3[3]);
    storeT(wbuf, off, t0, t1, t2, t3);
}

// single-matrix layer (helper for peel only): 6 MFMAs, 3 chains of 2.
__device__ __forceinline__ void layerT_one(
    const bf16x8& s0, const bf16x8& s1, const bf16x8& s2, const bf16x8& s3,
    const bf16x8& Ah0, const bf16x8& Ah1, const bf16x8& Al0, const bf16x8& Al1,
    const f32x4& cinit, short* wbuf, int off)
{
    f32x4 z = {0.f, 0.f, 0.f, 0.f};
    f32x4 a0 = cinit, a1 = z, a2 = z;
    a0 = MFMA(Ah0, s0, a0);  a1 = MFMA(Ah0, s2, a1);  a2 = MFMA(Al0, s0, a2);
    a0 = MFMA(Ah1, s1, a0);  a1 = MFMA(Ah1, s3, a1);  a2 = MFMA(Al1, s1, a2);
    float t0 = tanh_fast(a0[0] + a1[0] + a2[0]);
    float t1 = tanh_fast(a0[1] + a1[1] + a2[1]);
    float t2 = tanh_fast(a0[2] + a1[2] + a2[2]);
    float t3 = tanh_fast(a0[3] + a1[3] + a2[3]);
    storeT(wbuf, off, t0, t1, t2, t3);
}

// One pipeline phase, HAND-INTERLEAVED across the three independent layers:
// all 12 ds_reads -> 30 MFMAs round-robin over 11 chains (dep spacing 11) ->
// 12 sums+tanh -> 3 stores -> ONE barrier. Reads parity-q arrays, writes
// parity-p arrays (disjoint), so no mid-phase barrier is required.
__device__ __forceinline__ void phaseI(
    const short* r1, const short* r2, const short* r3,
    short* w1, short* w2, short* w3,
    int bcol, int g, int wbyte, float xf,
    const f32x4& b1v, const f32x4& b2v, const f32x4& b3v, const f32x4& w1f,
    const bf16x8& A1h0, const bf16x8& A1h1, const bf16x8& A1l0, const bf16x8& A1l1,
    const bf16x8& I2h0, const bf16x8& I2h1, const bf16x8& I2l0, const bf16x8& I2l1,
    const bf16x8& H2h0, const bf16x8& H2h1, const bf16x8& H2l0, const bf16x8& H2l1,
    const bf16x8& I3h0, const bf16x8& I3h1, const bf16x8& I3l0, const bf16x8& I3l1,
    const bf16x8& H3h0, const bf16x8& H3h1, const bf16x8& H3l0, const bf16x8& H3l1)
{
    bf16x8 s1_0 = ldsA(r1, bcol, 0, g), s1_1 = ldsA(r1, bcol, 1, g);
    bf16x8 s1_2 = ldsA(r1, bcol, 2, g), s1_3 = ldsA(r1, bcol, 3, g);
    bf16x8 f2_0 = ldsA(r2, bcol, 0, g), f2_1 = ldsA(r2, bcol, 1, g);
    bf16x8 f2_2 = ldsA(r2, bcol, 2, g), f2_3 = ldsA(r2, bcol, 3, g);
    bf16x8 s3_0 = ldsA(r3, bcol, 0, g), s3_1 = ldsA(r3, bcol, 1, g);
    bf16x8 s3_2 = ldsA(r3, bcol, 2, g), s3_3 = ldsA(r3, bcol, 3, g);

    f32x4 c1i;
    c1i[0] = fmaf(w1f[0], xf, b1v[0]);
    c1i[1] = fmaf(w1f[1], xf, b1v[1]);
    c1i[2] = fmaf(w1f[2], xf, b1v[2]);
    c1i[3] = fmaf(w1f[3], xf, b1v[3]);

    f32x4 z = {0.f, 0.f, 0.f, 0.f};
    f32x4 p0 = b2v, p1 = z, p2 = z, p3 = z;   // L2 chains
    f32x4 q0 = b3v, q1 = z, q2 = z, q3 = z;   // L3 chains
    f32x4 u0 = c1i, u1 = z, u2 = z;           // L1 chains

    // round 0 (chain element 0)
    p0 = MFMA(I2h0, s1_0, p0);
    p1 = MFMA(H2h0, f2_0, p1);
    p2 = MFMA(I2h0, s1_2, p2);
    p3 = MFMA(H2h0, f2_2, p3);
    q0 = MFMA(I3h0, f2_0, q0);
    q1 = MFMA(H3h0, s3_0, q1);
    q2 = MFMA(I3h0, f2_2, q2);
    q3 = MFMA(H3h0, s3_2, q3);
    u0 = MFMA(A1h0, s1_0, u0);
    u1 = MFMA(A1h0, s1_2, u1);
    u2 = MFMA(A1l0, s1_0, u2);
    // round 1 (chain element 1)
    p0 = MFMA(I2h1, s1_1, p0);
    p1 = MFMA(H2h1, f2_1, p1);
    p2 = MFMA(I2h1, s1_3, p2);
    p3 = MFMA(H2h1, f2_3, p3);
    q0 = MFMA(I3h1, f2_1, q0);
    q1 = MFMA(H3h1, s3_1, q1);
    q2 = MFMA(I3h1, f2_3, q2);
    q3 = MFMA(H3h1, s3_3, q3);
    u0 = MFMA(A1h1, s1_1, u0);
    u1 = MFMA(A1h1, s1_3, u1);
    u2 = MFMA(A1l1, s1_1, u2);
    // round 2 (chain element 2; L1 chains done)
    p0 = MFMA(H2l0, f2_0, p0);
    p1 = MFMA(I2l0, s1_0, p1);
    p2 = MFMA(H2l1, f2_1, p2);
    p3 = MFMA(I2l1, s1_1, p3);
    q0 = MFMA(H3l0, s3_0, q0);
    q1 = MFMA(I3l0, f2_0, q1);
    q2 = MFMA(H3l1, s3_1, q2);
    q3 = MFMA(I3l1, f2_1, q3);

    // epilogue: sums + tanh + stores (L2 first: its chains retire earliest)
    float t0 = tanh_fast((p0[0] + p1[0]) + (p2[0] + p3[0]));
    float t1 = tanh_fast((p0[1] + p1[1]) + (p2[1] + p3[1]));
    float t2 = tanh_fast((p0[2] + p1[2]) + (p2[2] + p3[2]));
    float t3 = tanh_fast((p0[3] + p1[3]) + (p2[3] + p3[3]));
    storeT(w2, wbyte, t0, t1, t2, t3);
    t0 = tanh_fast((q0[0] + q1[0]) + (q2[0] + q3[0]));
    t1 = tanh_fast((q0[1] + q1[1]) + (q2[1] + q3[1]));
    t2 = tanh_fast((q0[2] + q1[2]) + (q2[2] + q3[2]));
    t3 = tanh_fast((q0[3] + q1[3]) + (q2[3] + q3[3]));
    storeT(w3, wbyte, t0, t1, t2, t3);
    t0 = tanh_fast(u0[0] + u1[0] + u2[0]);
    t1 = tanh_fast(u0[1] + u1[1] + u2[1]);
    t2 = tanh_fast(u0[2] + u1[2] + u2[2]);
    t3 = tanh_fast(u0[3] + u1[3] + u2[3]);
    storeT(w1, wbyte, t0, t1, t2, t3);
    __syncthreads();
}

__global__ __launch_bounds__(256, 1)
void rnn3_kernel(const float* __restrict__ x,
                 const float* __restrict__ Wih1, const float* __restrict__ Whh1,
                 const float* __restrict__ bih1, const float* __restrict__ bhh1,
                 const float* __restrict__ Wih2, const float* __restrict__ Whh2,
                 const float* __restrict__ bih2, const float* __restrict__ bhh2,
                 const float* __restrict__ Wih3, const float* __restrict__ Whh3,
                 const float* __restrict__ bih3, const float* __restrict__ bhh3,
                 const float* __restrict__ Wfc,  const float* __restrict__ bfc,
                 float* __restrict__ out)
{
    __shared__ __align__(16) short h1s[2][2048];
    __shared__ __align__(16) short h2s[2][2048];
    __shared__ __align__(16) short h3s[2][2048];
    __shared__ float xls[512 * 17 + 32];   // x as f32, stride-17 pad

    const int tid  = threadIdx.x;
    const int lane = tid & 63;
    const int w    = tid >> 6;
    const int g    = lane >> 4;
    const int l15  = lane & 15;
    const int jrow = (w << 4) | l15;        // A-frag weight row
    const int bcol = l15;                   // B-frag / D batch row
    const int jout0 = (w << 4) + (g << 2);  // lane's 4 output hidden cols
    const int b0   = blockIdx.x * 16;

    // ---- zero-init ALL h buffers (uninit reads become 0, never NaN) ----
    { int* z1 = (int*)h1s; int* z2 = (int*)h2s; int* z3 = (int*)h3s;
      for (int k = tid; k < 2048; k += 256) { z1[k] = 0; z2[k] = 0; z3[k] = 0; } }

    // ---- stage x as f32 [t][b] (stride 17) ----
    {
        const float4* xg = (const float4*)(x + (size_t)b0 * 512);
        for (int idx = tid; idx < 2048; idx += 256) {   // 16 rows * 128 float4
            float4 v = xg[idx];
            int b = idx >> 7, t0 = (idx & 127) << 2;
            xls[(t0 + 0) * 17 + b] = v.x;
            xls[(t0 + 1) * 17 + b] = v.y;
            xls[(t0 + 2) * 17 + b] = v.z;
            xls[(t0 + 3) * 17 + b] = v.w;
        }
    }

    // ---- persistent weight fragments (hi + lo residual) ----
    const int k8 = g << 3;
    bf16x8 A1h0, A1l0, A1h1, A1l1;
    makeA2(Whh1, jrow, k8,      A1h0, A1l0);
    makeA2(Whh1, jrow, 32 + k8, A1h1, A1l1);
    bf16x8 I2h0, I2l0, I2h1, I2l1;
    makeA2(Wih2, jrow, k8,      I2h0, I2l0);
    makeA2(Wih2, jrow, 32 + k8, I2h1, I2l1);
    bf16x8 H2h0, H2l0, H2h1, H2l1;
    makeA2(Whh2, jrow, k8,      H2h0, H2l0);
    makeA2(Whh2, jrow, 32 + k8, H2h1, H2l1);
    bf16x8 I3h0, I3l0, I3h1, I3l1;
    makeA2(Wih3, jrow, k8,      I3h0, I3l0);
    makeA2(Wih3, jrow, 32 + k8, I3h1, I3l1);
    bf16x8 H3h0, H3l0, H3h1, H3l1;
    makeA2(Whh3, jrow, k8,      H3h0, H3l0);
    makeA2(Whh3, jrow, 32 + k8, H3h1, H3l1);

    f32x4 b1v, b2v, b3v, w1f;
#pragma unroll
    for (int r = 0; r < 4; ++r) {
        int j = jout0 + r;
        bool v = j < 50;
        b1v[r] = v ? (bih1[j] + bhh1[j]) : 0.0f;
        b2v[r] = v ? (bih2[j] + bhh2[j]) : 0.0f;
        b3v[r] = v ? (bih3[j] + bhh3[j]) : 0.0f;
        w1f[r] = v ? Wih1[j] : 0.0f;
    }

    const int wbyte = swz(bcol, jout0 << 1);

    __syncthreads();   // x staged, h buffers zeroed

    // ---- phase 0: L1(0) (all states zero -> pure scalar path) -> h1[0] ----
    {
        float xf = xls[bcol];
        float t0 = tanh_fast(fmaf(w1f[0], xf, b1v[0]));
        float t1 = tanh_fast(fmaf(w1f[1], xf, b1v[1]));
        float t2 = tanh_fast(fmaf(w1f[2], xf, b1v[2]));
        float t3 = tanh_fast(fmaf(w1f[3], xf, b1v[3]));
        storeT(h1s[0], wbyte, t0, t1, t2, t3);
        __syncthreads();
    }
    // ---- phase 1: L1(1) -> h1[1], L2(0) (ih-only) -> h2[1] ----
    {
        bf16x8 s1_0 = ldsA(h1s[0], bcol, 0, g), s1_1 = ldsA(h1s[0], bcol, 1, g);
        bf16x8 s1_2 = ldsA(h1s[0], bcol, 2, g), s1_3 = ldsA(h1s[0], bcol, 3, g);
        float xf = xls[17 + bcol];
        f32x4 c1i;
        c1i[0] = fmaf(w1f[0], xf, b1v[0]);
        c1i[1] = fmaf(w1f[1], xf, b1v[1]);
        c1i[2] = fmaf(w1f[2], xf, b1v[2]);
        c1i[3] = fmaf(w1f[3], xf, b1v[3]);
        layerT_one(s1_0, s1_1, s1_2, s1_3, I2h0, I2h1, I2l0, I2l1, b2v, h2s[1], wbyte);
        layerT_one(s1_0, s1_1, s1_2, s1_3, A1h0, A1h1, A1l0, A1l1, c1i, h1s[1], wbyte);
        __syncthreads();
    }

    // ---- main phases i=2..511 (manual 2x unroll, compile-time parities) ----
    for (int i = 2; i < 512; i += 2) {
        // even phase: read parity 1, write parity 0
        phaseI(h1s[1], h2s[1], h3s[1], h1s[0], h2s[0], h3s[0],
               bcol, g, wbyte, xls[i * 17 + bcol],
               b1v, b2v, b3v, w1f,
               A1h0, A1h1, A1l0, A1l1,
               I2h0, I2h1, I2l0, I2l1, H2h0, H2h1, H2l0, H2l1,
               I3h0, I3h1, I3l0, I3l1, H3h0, H3h1, H3l0, H3l1);
        // odd phase: read parity 0, write parity 1
        phaseI(h1s[0], h2s[0], h3s[0], h1s[1], h2s[1], h3s[1],
               bcol, g, wbyte, xls[(i + 1) * 17 + bcol],
               b1v, b2v, b3v, w1f,
               A1h0, A1h1, A1l0, A1l1,
               I2h0, I2h1, I2l0, I2l1, H2h0, H2h1, H2l0, H2l1,
               I3h0, I3h1, I3l0, I3l1, H3h0, H3h1, H3l0, H3l1);
    }

    // ---- phase 512: L2(511) -> h2[0], L3(510) -> h3[0] ----
    {
        bf16x8 s1_0 = ldsA(h1s[1], bcol, 0, g), s1_1 = ldsA(h1s[1], bcol, 1, g);
        bf16x8 s1_2 = ldsA(h1s[1], bcol, 2, g), s1_3 = ldsA(h1s[1], bcol, 3, g);
        bf16x8 f2_0 = ldsA(h2s[1], bcol, 0, g), f2_1 = ldsA(h2s[1], bcol, 1, g);
        bf16x8 f2_2 = ldsA(h2s[1], bcol, 2, g), f2_3 = ldsA(h2s[1], bcol, 3, g);
        bf16x8 s3_0 = ldsA(h3s[1], bcol, 0, g), s3_1 = ldsA(h3s[1], bcol, 1, g);
        bf16x8 s3_2 = ldsA(h3s[1], bcol, 2, g), s3_3 = ldsA(h3s[1], bcol, 3, g);
        __syncthreads();
        layerT_full(s1_0, s1_1, s1_2, s1_3, f2_0, f2_1, f2_2, f2_3,
                    I2h0, I2h1, I2l0, I2l1, H2h0, H2h1, H2l0, H2l1,
                    b2v, h2s[0], wbyte);
        layerT_full(f2_0, f2_1, f2_2, f2_3, s3_0, s3_1, s3_2, s3_3,
                    I3h0, I3h1, I3l0, I3l1, H3h0, H3h1, H3l0, H3l1,
                    b3v, h3s[0], wbyte);
        __syncthreads();
    }
    // ---- phase 513: L3(511) -> h3[1] ----
    {
        bf16x8 f2_0 = ldsA(h2s[0], bcol, 0, g), f2_1 = ldsA(h2s[0], bcol, 1, g);
        bf16x8 f2_2 = ldsA(h2s[0], bcol, 2, g), f2_3 = ldsA(h2s[0], bcol, 3, g);
        bf16x8 s3_0 = ldsA(h3s[0], bcol, 0, g), s3_1 = ldsA(h3s[0], bcol, 1, g);
        bf16x8 s3_2 = ldsA(h3s[0], bcol, 2, g), s3_3 = ldsA(h3s[0], bcol, 3, g);
        __syncthreads();
        layerT_full(f2_0, f2_1, f2_2, f2_3, s3_0, s3_1, s3_2, s3_3,
                    I3h0, I3h1, I3l0, I3l1, H3h0, H3h1, H3l0, H3l1,
                    b3v, h3s[1], wbyte);
        __syncthreads();
    }

    // ---- FC epilogue: out[b][o] = (h3_hi + h3_lo) @ Wfc^T + bfc ----
    {
        const short* h3f = h3s[1];
        int o = (w << 2) | g;           // 0..15, valid < 10
        int b = bcol;
        if (o < 10) {
            float acc = bfc[o];
            for (int k = 0; k < 50; ++k)
                acc += (ldsR(h3f, b, k) + ldsR(h3f, b, 64 + k)) * Wfc[o * 50 + k];
            out[(size_t)(b0 + b) * 10 + o] = acc;
        }
    }
}

extern "C" void kernel_launch(void* const* d_in, const int* in_sizes, int n_in,
                              void* d_out, int out_size, void* d_ws, size_t ws_size,
                              hipStream_t stream) {
    const float* x    = (const float*)d_in[0];
    const float* Wih1 = (const float*)d_in[1];
    const float* Whh1 = (const float*)d_in[2];
    const float* bih1 = (const float*)d_in[3];
    const float* bhh1 = (const float*)d_in[4];
    const float* Wih2 = (const float*)d_in[5];
    const float* Whh2 = (const float*)d_in[6];
    const float* bih2 = (const float*)d_in[7];
    const float* bhh2 = (const float*)d_in[8];
    const float* Wih3 = (const float*)d_in[9];
    const float* Whh3 = (const float*)d_in[10];
    const float* bih3 = (const float*)d_in[11];
    const float* bhh3 = (const float*)d_in[12];
    const float* Wfc  = (const float*)d_in[13];
    const float* bfc  = (const float*)d_in[14];
    float* out = (float*)d_out;

    dim3 grid(256), block(256);
    hipLaunchKernelGGL(rnn3_kernel, grid, block, 0, stream,
                       x, Wih1, Whh1, bih1, bhh1,
                       Wih2, Whh2, bih2, bhh2,
                       Wih3, Whh3, bih3, bhh3,
                       Wfc, bfc, out);
}